// Round 4
// baseline (273.834 us; speedup 1.0000x reference)
//
#include <hip/hip_runtime.h>
#include <math.h>

#define NPOS 4096   // H*W
#define MTOT 8192   // B*NPOS
#define KP   352    // padded feature dim (323 -> 352, mult of 32)
#define HT 64
#define WT 64

typedef unsigned short ushortT;
typedef short v8s __attribute__((ext_vector_type(8)));
typedef float v4f __attribute__((ext_vector_type(4)));

static __device__ __forceinline__ ushortT bfr(float f) {
    union { float f; unsigned u; } v; v.f = f;
    return (ushortT)((v.u + 0x8000u) >> 16);
}
// round-half-up pack (projections)
static __device__ __forceinline__ unsigned pack2bf(float a, float b) {
    union { float f; unsigned u; } ua, ub; ua.f = a; ub.f = b;
    return __builtin_amdgcn_perm(ub.u + 0x8000u, ua.u + 0x8000u, 0x07060302u);
}
// truncating pack (P values; error < 0.4% relative, softmax-safe) — 1 instr
static __device__ __forceinline__ unsigned pack2bf_t(float a, float b) {
    union { float f; unsigned u; } ua, ub; ua.f = a; ub.f = b;
    return __builtin_amdgcn_perm(ub.u, ua.u, 0x07060302u);
}
static __device__ __forceinline__ float fexp2(float x) {
#if __has_builtin(__builtin_amdgcn_exp2f)
    return __builtin_amdgcn_exp2f(x);
#else
    return exp2f(x);
#endif
}

// ---------------- per-batch min/max of dsm ----------------
__global__ void k_minmax(const float* __restrict__ dsm, float* __restrict__ mm) {
    int b = blockIdx.x;
    const float* p = dsm + (size_t)b * NPOS;
    float mn = 1e30f, mx = -1e30f;
    for (int i = threadIdx.x; i < NPOS; i += 256) {
        float v = p[i];
        mn = fminf(mn, v); mx = fmaxf(mx, v);
    }
    for (int off = 32; off; off >>= 1) {
        mn = fminf(mn, __shfl_xor(mn, off, 64));
        mx = fmaxf(mx, __shfl_xor(mx, off, 64));
    }
    __shared__ float smn[4], smx[4];
    int wid = threadIdx.x >> 6;
    if ((threadIdx.x & 63) == 0) { smn[wid] = mn; smx[wid] = mx; }
    __syncthreads();
    if (threadIdx.x == 0) {
        mn = fminf(fminf(smn[0], smn[1]), fminf(smn[2], smn[3]));
        mx = fmaxf(fmaxf(smx[0], smx[1]), fmaxf(smx[2], smx[3]));
        mm[b * 2 + 0] = mn; mm[b * 2 + 1] = mx;
    }
}

// ---------------- prep: d/gx/gy/PE -> F cols 256..351 (bf16), alpha fp32 ----------------
__global__ void k_prep(const float* __restrict__ dsm, const float* __restrict__ mm,
                       const float* __restrict__ walpha, const float* __restrict__ balpha,
                       ushortT* __restrict__ F, float* __restrict__ alpha) {
    int idx = blockIdx.x * 256 + threadIdx.x;    // global m, 0..8191
    int b = idx / NPOS, n = idx % NPOS;
    int hh = n / WT, ww = n % WT;
    float dmin = mm[b * 2], dmax = mm[b * 2 + 1];
    float inv = 1.0f / (dmax - dmin + 1e-6f);
    const float* dp = dsm + (size_t)b * NPOS;

    float dwin[5][5];
    #pragma unroll
    for (int dy = 0; dy < 5; dy++)
        #pragma unroll
        for (int dx = 0; dx < 5; dx++) {
            int y = hh + dy - 2, x = ww + dx - 2;
            float v = 0.0f;
            if (y >= 0 && y < HT && x >= 0 && x < WT) v = (dp[y * WT + x] - dmin) * inv;
            dwin[dy][dx] = v;
        }

    float gxc = 0.f, gyc = 0.f;
    float conv = 0.f;
    #pragma unroll
    for (int oy = 0; oy < 3; oy++)
        #pragma unroll
        for (int ox = 0; ox < 3; ox++) {
            int qy = hh + oy - 1, qx = ww + ox - 1;
            float m = 0.0f;
            if (qy >= 0 && qy < HT && qx >= 0 && qx < WT) {
                float gx = dwin[oy][ox] - dwin[oy][ox + 2]
                         + 2.f * dwin[oy + 1][ox] - 2.f * dwin[oy + 1][ox + 2]
                         + dwin[oy + 2][ox] - dwin[oy + 2][ox + 2];
                float gy = dwin[oy][ox] + 2.f * dwin[oy][ox + 1] + dwin[oy][ox + 2]
                         - dwin[oy + 2][ox] - 2.f * dwin[oy + 2][ox + 1] - dwin[oy + 2][ox + 2];
                if (oy == 1 && ox == 1) { gxc = gx; gyc = gy; }
                float rx = fmaxf(gx, 0.f), ry = fmaxf(gy, 0.f);
                m = sqrtf(rx * rx + ry * ry + 1e-12f);
            }
            conv += walpha[oy * 3 + ox] * m;
        }
    alpha[idx] = 1.f / (1.f + __expf(-(conv + balpha[0])));

    ushortT* fb = F + (size_t)idx * KP;
    fb[256] = bfr(dwin[2][2]);
    fb[257] = bfr(gxc);
    fb[258] = bfr(gyc);
    float xc = -1.f + 2.f * (float)ww / 63.f;
    float yc = -1.f + 2.f * (float)hh / 63.f;
    const float l2w = 13.287712379549449f;  // log2(10000)
    #pragma unroll
    for (int i = 0; i < 16; i++) {
        float omega = exp2f(-(float)i * (l2w / 16.f));   // constant-folds per unrolled i
        float px = xc * omega, py = yc * omega;
        fb[259 + i]      = bfr(__sinf(px));
        fb[259 + 16 + i] = bfr(__cosf(px));
        fb[259 + 32 + i] = bfr(__sinf(py));
        fb[259 + 48 + i] = bfr(__cosf(py));
    }
    #pragma unroll
    for (int z = 323; z < KP; z++) fb[z] = 0;
}

// ---------------- cast x -> F cols 0..255 (bf16, LDS transpose) ----------------
__global__ void k_cast(const float* __restrict__ x, ushortT* __restrict__ F) {
    __shared__ __align__(16) ushortT Tl[64][72];
    int nt = blockIdx.x * 64;
    int b = blockIdx.y >> 2, ct = (blockIdx.y & 3) * 64;
    int t = threadIdx.x;
    #pragma unroll
    for (int rep = 0; rep < 4; rep++) {
        int row = rep * 16 + (t >> 4), c4 = (t & 15) * 4;
        float4 f4 = *(const float4*)&x[((size_t)(b * 256 + ct + row)) * NPOS + nt + c4];
        Tl[c4 + 0][row] = bfr(f4.x);
        Tl[c4 + 1][row] = bfr(f4.y);
        Tl[c4 + 2][row] = bfr(f4.z);
        Tl[c4 + 3][row] = bfr(f4.w);
    }
    __syncthreads();
    #pragma unroll
    for (int rep = 0; rep < 2; rep++) {
        int slot = rep * 256 + t, row = slot >> 3, c8 = slot & 7;
        *(uint4*)&F[((size_t)(b * 4096 + nt + row)) * KP + ct + c8 * 8] = *(uint4*)&Tl[row][c8 * 8];
    }
}

// ---------------- combined weight Wc[1536][352] bf16 + bias fp32 ----------------
__global__ void k_wcprep(const float* __restrict__ wq, const float* __restrict__ wkv,
                         const float* __restrict__ whape, const float* __restrict__ bhape,
                         ushortT* __restrict__ Wc, float* __restrict__ biasc) {
    int idx = blockIdx.x * 256 + threadIdx.x;   // o*KP + k
    int o = idx / KP, k = idx % KP;
    float v = 0.f;
    if (o < 512) {
        if (k < 256) v = wq[o * 256 + k] * 0.18033688011112042f;  // 0.125 * log2(e)
        if (k == 0) biasc[o] = 0.f;
    } else if (o < 1024) {
        int r = o - 512;
        if (k < 257) v = wkv[r * 257 + k];
        if (k == 256)      v += whape[r * 67 + 64];
        else if (k == 257) v = whape[r * 67 + 65];
        else if (k == 258) v = whape[r * 67 + 66];
        else if (k >= 259 && k < 323) v = whape[r * 67 + (k - 259)];
        if (k == 0) biasc[o] = bhape[r];
    } else {
        int r = o - 512;
        if (k < 257) v = wkv[r * 257 + k];
        if (k == 0) biasc[o] = 0.f;
    }
    Wc[idx] = bfr(v);
}

// ---------------- wout -> bf16 ----------------
__global__ void k_wout(const float* __restrict__ wout, ushortT* __restrict__ woutb) {
    int idx = blockIdx.x * 256 + threadIdx.x;   // 131072
    woutb[idx] = bfr(wout[idx]);
}

// ---------------- GEMM1 (bf16 MFMA): [1536]x[352]x[8192] -> qT/kT/vv ----------------
__global__ __launch_bounds__(256) void k_gemm1(const ushortT* __restrict__ Wc, const ushortT* __restrict__ F,
                                               const float* __restrict__ biasc,
                                               ushortT* __restrict__ qT, ushortT* __restrict__ kT,
                                               ushortT* __restrict__ vv) {
    __shared__ __align__(16) ushortT Al[64][40];
    __shared__ __align__(16) ushortT Bl[64][40];
    __shared__ __align__(16) ushortT Vt[64][72];
    int mt = blockIdx.x * 64;
    int ot = blockIdx.y * 64;
    int t = threadIdx.x, w = t >> 6, lane = t & 63, u = lane & 15, quad = lane >> 4;
    int arow = t >> 2, ac8 = t & 3;
    v4f acc[4] = {};
    for (int k0 = 0; k0 < KP; k0 += 32) {
        __syncthreads();
        *(uint4*)&Al[arow][ac8 * 8] = *(const uint4*)&Wc[(size_t)(ot + arow) * KP + k0 + ac8 * 8];
        *(uint4*)&Bl[arow][ac8 * 8] = *(const uint4*)&F[(size_t)(mt + arow) * KP + k0 + ac8 * 8];
        __syncthreads();
        v8s a = *(v8s*)&Al[w * 16 + u][quad * 8];
        #pragma unroll
        for (int n4 = 0; n4 < 4; n4++) {
            v8s bb = *(v8s*)&Bl[n4 * 16 + u][quad * 8];
            acc[n4] = __builtin_amdgcn_mfma_f32_16x16x32_bf16(a, bb, acc[n4], 0, 0, 0);
        }
    }
    int obase = ot + w * 16 + quad * 4;
    float bo[4];
    #pragma unroll
    for (int r = 0; r < 4; r++) bo[r] = biasc[obase + r];
    if (ot < 1024) {
        int h = (ot >> 6) & 7;
        ushortT* dst = (ot < 512) ? qT : kT;
        #pragma unroll
        for (int n4 = 0; n4 < 4; n4++) {
            int m = mt + n4 * 16 + u;
            uint2 val;
            val.x = pack2bf(acc[n4][0] + bo[0], acc[n4][1] + bo[1]);
            val.y = pack2bf(acc[n4][2] + bo[2], acc[n4][3] + bo[3]);
            *(uint2*)&dst[((size_t)h * MTOT + m) * 64 + w * 16 + quad * 4] = val;
        }
    } else {
        __syncthreads();
        #pragma unroll
        for (int n4 = 0; n4 < 4; n4++) {
            int ml = n4 * 16 + u;
            #pragma unroll
            for (int r = 0; r < 4; r++) Vt[w * 16 + quad * 4 + r][ml] = bfr(acc[n4][r] + bo[r]);
        }
        __syncthreads();
        #pragma unroll
        for (int rep = 0; rep < 2; rep++) {
            int slot = rep * 256 + t, row = slot >> 3, c8 = slot & 7;
            *(uint4*)&vv[(size_t)(ot - 1024 + row) * MTOT + mt + c8 * 8] = *(uint4*)&Vt[row][c8 * 8];
        }
    }
}

// ---------------- flash attention: barrier-free K-loop, direct-global fragments ----------------
// Block: 4 waves x 64 queries = 256 queries. Grid (16, 16).
// S^T = K*Q^T (C: col=query=lane&15), O^T = V^T*P. K/V/Q fragments loaded straight
// from global (L1-resident 16KB/chunk tiles, shared by the 4 waves). Only P goes
// through LDS (per-wave strip, XOR-swizzled, within-wave lgkmcnt — no barriers).
#define LIDX(row, cb) (((row) << 6) + ((((cb) ^ ((row) & 7))) << 3))
__global__ __launch_bounds__(256, 2) void k_flash(const ushortT* __restrict__ qT,
                                                  const ushortT* __restrict__ kT,
                                                  const ushortT* __restrict__ vv,
                                                  ushortT* __restrict__ aoB) {
    __shared__ __align__(16) ushortT Pw[4][64 * 64];   // per-wave P strip, 8 KB each

    int it = blockIdx.x;           // 0..15 (256-query tiles)
    int bh = blockIdx.y;
    int b = bh >> 3, h = bh & 7;
    int colbase = b * NPOS;
    int t = threadIdx.x, w = t >> 6, lane = t & 63, u = lane & 15, quad = lane >> 4;
    int qb = it * 256 + w * 64;    // wave's query base within batch

    const ushortT* Qg = qT + ((size_t)h * MTOT + colbase + qb) * 64;
    const ushortT* Kg = kT + ((size_t)h * MTOT + colbase) * 64;
    const ushortT* Vg = vv + ((size_t)(h * 64)) * MTOT + colbase;
    ushortT* P = &Pw[w][0];

    // Q fragments: resident in registers for the whole K-loop
    v8s bq[4][2];
    #pragma unroll
    for (int g = 0; g < 4; g++)
        #pragma unroll
        for (int hf = 0; hf < 2; hf++)
            bq[g][hf] = *(const v8s*)&Qg[(size_t)(g * 16 + u) * 64 + hf * 32 + quad * 8];

    float li[4] = {0.f, 0.f, 0.f, 0.f};
    v4f O[4][4] = {};   // [d4][g]

    for (int jc = 0; jc < 64; jc++) {
        int jb = jc * 64;
        // fragment loads straight from global (vmcnt-overlapped with MFMA)
        v8s ka[4][2], va[4][2];
        #pragma unroll
        for (int k4 = 0; k4 < 4; k4++)
            #pragma unroll
            for (int hf = 0; hf < 2; hf++)
                ka[k4][hf] = *(const v8s*)&Kg[(size_t)(jb + k4 * 16 + u) * 64 + hf * 32 + quad * 8];
        #pragma unroll
        for (int d4 = 0; d4 < 4; d4++)
            #pragma unroll
            for (int ks = 0; ks < 2; ks++)
                va[d4][ks] = *(const v8s*)&Vg[(size_t)(d4 * 16 + u) * MTOT + jb + ks * 32 + quad * 8];

        // S^T tiles + softmax, k4-strip at a time (keeps st live-range small)
        #pragma unroll
        for (int k4 = 0; k4 < 4; k4++) {
            v4f st[4];
            #pragma unroll
            for (int g = 0; g < 4; g++) {
                st[g] = (v4f){0.f, 0.f, 0.f, 0.f};
                st[g] = __builtin_amdgcn_mfma_f32_16x16x32_bf16(ka[k4][0], bq[g][0], st[g], 0, 0, 0);
                st[g] = __builtin_amdgcn_mfma_f32_16x16x32_bf16(ka[k4][1], bq[g][1], st[g], 0, 0, 0);
            }
            #pragma unroll
            for (int g = 0; g < 4; g++) {
                float p0 = fexp2(st[g][0]);
                float p1 = fexp2(st[g][1]);
                float p2 = fexp2(st[g][2]);
                float p3 = fexp2(st[g][3]);
                li[g] += (p0 + p1) + (p2 + p3);
                uint2 pv; pv.x = pack2bf_t(p0, p1); pv.y = pack2bf_t(p2, p3);
                *(uint2*)&P[LIDX(g * 16 + u, k4 * 2 + (quad >> 1)) + (quad & 1) * 4] = pv;
            }
        }

        // O^T += V^T * P   (P read back as B fragments; same-wave lgkmcnt only)
        v8s bp[4][2];
        #pragma unroll
        for (int g = 0; g < 4; g++)
            #pragma unroll
            for (int ks = 0; ks < 2; ks++)
                bp[g][ks] = *(v8s*)&P[LIDX(g * 16 + u, ks * 4 + quad)];
        #pragma unroll
        for (int d4 = 0; d4 < 4; d4++)
            #pragma unroll
            for (int g = 0; g < 4; g++) {
                O[d4][g] = __builtin_amdgcn_mfma_f32_16x16x32_bf16(va[d4][0], bp[g][0], O[d4][g], 0, 0, 0);
                O[d4][g] = __builtin_amdgcn_mfma_f32_16x16x32_bf16(va[d4][1], bp[g][1], O[d4][g], 0, 0, 0);
            }
    }

    #pragma unroll
    for (int g = 0; g < 4; g++) {
        li[g] += __shfl_xor(li[g], 16, 64);
        li[g] += __shfl_xor(li[g], 32, 64);
        float inv = 1.f / li[g];
        size_t base = (size_t)(colbase + qb + g * 16 + u) * 512 + h * 64;
        #pragma unroll
        for (int d4 = 0; d4 < 4; d4++) {
            uint2 val;
            val.x = pack2bf(O[d4][g][0] * inv, O[d4][g][1] * inv);
            val.y = pack2bf(O[d4][g][2] * inv, O[d4][g][3] * inv);
            *(uint2*)&aoB[base + d4 * 16 + quad * 4] = val;
        }
    }
}

// ---------------- GEMM2 (bf16 MFMA): out = x + (wout*AO + bout)*alpha ----------------
__global__ __launch_bounds__(256) void k_gemm2(const ushortT* __restrict__ woutb, const ushortT* __restrict__ aoB,
                                               const float* __restrict__ bout, const float* __restrict__ x,
                                               const float* __restrict__ alpha, float* __restrict__ out) {
    __shared__ __align__(16) ushortT Al[64][40];
    __shared__ __align__(16) ushortT Bl[64][40];
    int mt = blockIdx.x * 64;
    int ot = blockIdx.y * 64;
    int t = threadIdx.x, w = t >> 6, lane = t & 63, u = lane & 15, quad = lane >> 4;
    int arow = t >> 2, ac8 = t & 3;
    v4f acc[4] = {};
    for (int k0 = 0; k0 < 512; k0 += 32) {
        __syncthreads();
        *(uint4*)&Al[arow][ac8 * 8] = *(const uint4*)&woutb[(size_t)(ot + arow) * 512 + k0 + ac8 * 8];
        *(uint4*)&Bl[arow][ac8 * 8] = *(const uint4*)&aoB[(size_t)(mt + arow) * 512 + k0 + ac8 * 8];
        __syncthreads();
        v8s a = *(v8s*)&Al[w * 16 + u][quad * 8];
        #pragma unroll
        for (int n4 = 0; n4 < 4; n4++) {
            v8s bb = *(v8s*)&Bl[n4 * 16 + u][quad * 8];
            acc[n4] = __builtin_amdgcn_mfma_f32_16x16x32_bf16(a, bb, acc[n4], 0, 0, 0);
        }
    }
    int b = mt >> 12, n0 = mt & 4095;
    int obase = ot + w * 16 + quad * 4;
    float bo[4];
    #pragma unroll
    for (int r = 0; r < 4; r++) bo[r] = bout[obase + r];
    #pragma unroll
    for (int n4 = 0; n4 < 4; n4++) {
        int n = n0 + n4 * 16 + u;
        float al = alpha[(size_t)b * NPOS + n];
        #pragma unroll
        for (int r = 0; r < 4; r++) {
            size_t xi = ((size_t)(b * 256 + obase + r)) * NPOS + n;
            out[xi] = x[xi] + (acc[n4][r] + bo[r]) * al;
        }
    }
}

extern "C" void kernel_launch(void* const* d_in, const int* in_sizes, int n_in,
                              void* d_out, int out_size, void* d_ws, size_t ws_size,
                              hipStream_t stream) {
    const float* x      = (const float*)d_in[0];
    const float* dsm    = (const float*)d_in[1];
    const float* wq     = (const float*)d_in[2];
    const float* wkv    = (const float*)d_in[3];
    const float* wout   = (const float*)d_in[4];
    const float* bout   = (const float*)d_in[5];
    const float* whape  = (const float*)d_in[6];
    const float* bhape  = (const float*)d_in[7];
    const float* walpha = (const float*)d_in[8];
    const float* balpha = (const float*)d_in[9];
    float* out = (float*)d_out;
    float* ws  = (float*)d_ws;

    size_t off = 0;
    float* mm    = ws + off; off += 256;
    float* alpha = ws + off; off += (size_t)2 * NPOS;
    float* biasc = ws + off; off += 2048;
    ushortT* F     = (ushortT*)(ws + off); off += (size_t)MTOT * KP / 2;
    ushortT* Wc    = (ushortT*)(ws + off); off += (size_t)1536 * KP / 2;
    ushortT* woutb = (ushortT*)(ws + off); off += (size_t)256 * 512 / 2;
    ushortT* qT    = (ushortT*)(ws + off); off += (size_t)8 * MTOT * 64 / 2;
    ushortT* kT    = (ushortT*)(ws + off); off += (size_t)8 * MTOT * 64 / 2;
    ushortT* vv    = (ushortT*)(ws + off); off += (size_t)512 * MTOT / 2;
    ushortT* aoB   = (ushortT*)(ws + off); off += (size_t)MTOT * 512 / 2;
    (void)in_sizes; (void)n_in; (void)out_size; (void)ws_size;

    k_minmax<<<2, 256, 0, stream>>>(dsm, mm);
    k_prep<<<32, 256, 0, stream>>>(dsm, mm, walpha, balpha, F, alpha);
    k_cast<<<dim3(64, 8), 256, 0, stream>>>(x, F);
    k_wcprep<<<(1536 * KP) / 256, 256, 0, stream>>>(wq, wkv, whape, bhape, Wc, biasc);
    k_wout<<<512, 256, 0, stream>>>(wout, woutb);
    k_gemm1<<<dim3(128, 24), 256, 0, stream>>>(Wc, F, biasc, qT, kT, vv);
    k_flash<<<dim3(16, 16), 256, 0, stream>>>(qT, kT, vv, aoB);
    k_gemm2<<<dim3(128, 4), 256, 0, stream>>>(woutb, aoB, bout, x, alpha, out);
}

// Round 5
// 212.833 us; speedup vs baseline: 1.2866x; 1.2866x over previous
//
#include <hip/hip_runtime.h>
#include <math.h>

#define NPOS 4096   // H*W
#define MTOT 8192   // B*NPOS
#define KP   352    // padded feature dim (323 -> 352, mult of 32)
#define HT 64
#define WT 64

typedef unsigned short ushortT;
typedef short v8s __attribute__((ext_vector_type(8)));
typedef float v4f __attribute__((ext_vector_type(4)));

static __device__ __forceinline__ ushortT bfr(float f) {
    union { float f; unsigned u; } v; v.f = f;
    return (ushortT)((v.u + 0x8000u) >> 16);
}
// round-half-up pack (projections)
static __device__ __forceinline__ unsigned pack2bf(float a, float b) {
    union { float f; unsigned u; } ua, ub; ua.f = a; ub.f = b;
    return __builtin_amdgcn_perm(ub.u + 0x8000u, ua.u + 0x8000u, 0x07060302u);
}
// truncating pack (P values; softmax-safe) — 1 instr
static __device__ __forceinline__ unsigned pack2bf_t(float a, float b) {
    union { float f; unsigned u; } ua, ub; ua.f = a; ub.f = b;
    return __builtin_amdgcn_perm(ub.u, ua.u, 0x07060302u);
}
static __device__ __forceinline__ float fexp2(float x) {
#if __has_builtin(__builtin_amdgcn_exp2f)
    return __builtin_amdgcn_exp2f(x);
#else
    return exp2f(x);
#endif
}

// ---------------- per-batch min/max of dsm ----------------
__global__ void k_minmax(const float* __restrict__ dsm, float* __restrict__ mm) {
    int b = blockIdx.x;
    const float* p = dsm + (size_t)b * NPOS;
    float mn = 1e30f, mx = -1e30f;
    for (int i = threadIdx.x; i < NPOS; i += 256) {
        float v = p[i];
        mn = fminf(mn, v); mx = fmaxf(mx, v);
    }
    for (int off = 32; off; off >>= 1) {
        mn = fminf(mn, __shfl_xor(mn, off, 64));
        mx = fmaxf(mx, __shfl_xor(mx, off, 64));
    }
    __shared__ float smn[4], smx[4];
    int wid = threadIdx.x >> 6;
    if ((threadIdx.x & 63) == 0) { smn[wid] = mn; smx[wid] = mx; }
    __syncthreads();
    if (threadIdx.x == 0) {
        mn = fminf(fminf(smn[0], smn[1]), fminf(smn[2], smn[3]));
        mx = fmaxf(fmaxf(smx[0], smx[1]), fmaxf(smx[2], smx[3]));
        mm[b * 2 + 0] = mn; mm[b * 2 + 1] = mx;
    }
}

// ---------------- prep: d/gx/gy/PE -> F cols 256..351 (bf16), alpha fp32 ----------------
__global__ void k_prep(const float* __restrict__ dsm, const float* __restrict__ mm,
                       const float* __restrict__ walpha, const float* __restrict__ balpha,
                       ushortT* __restrict__ F, float* __restrict__ alpha) {
    int idx = blockIdx.x * 256 + threadIdx.x;    // global m, 0..8191
    int b = idx / NPOS, n = idx % NPOS;
    int hh = n / WT, ww = n % WT;
    float dmin = mm[b * 2], dmax = mm[b * 2 + 1];
    float inv = 1.0f / (dmax - dmin + 1e-6f);
    const float* dp = dsm + (size_t)b * NPOS;

    float dwin[5][5];
    #pragma unroll
    for (int dy = 0; dy < 5; dy++)
        #pragma unroll
        for (int dx = 0; dx < 5; dx++) {
            int y = hh + dy - 2, x = ww + dx - 2;
            float v = 0.0f;
            if (y >= 0 && y < HT && x >= 0 && x < WT) v = (dp[y * WT + x] - dmin) * inv;
            dwin[dy][dx] = v;
        }

    float gxc = 0.f, gyc = 0.f;
    float conv = 0.f;
    #pragma unroll
    for (int oy = 0; oy < 3; oy++)
        #pragma unroll
        for (int ox = 0; ox < 3; ox++) {
            int qy = hh + oy - 1, qx = ww + ox - 1;
            float m = 0.0f;
            if (qy >= 0 && qy < HT && qx >= 0 && qx < WT) {
                float gx = dwin[oy][ox] - dwin[oy][ox + 2]
                         + 2.f * dwin[oy + 1][ox] - 2.f * dwin[oy + 1][ox + 2]
                         + dwin[oy + 2][ox] - dwin[oy + 2][ox + 2];
                float gy = dwin[oy][ox] + 2.f * dwin[oy][ox + 1] + dwin[oy][ox + 2]
                         - dwin[oy + 2][ox] - 2.f * dwin[oy + 2][ox + 1] - dwin[oy + 2][ox + 2];
                if (oy == 1 && ox == 1) { gxc = gx; gyc = gy; }
                float rx = fmaxf(gx, 0.f), ry = fmaxf(gy, 0.f);
                m = sqrtf(rx * rx + ry * ry + 1e-12f);
            }
            conv += walpha[oy * 3 + ox] * m;
        }
    alpha[idx] = 1.f / (1.f + __expf(-(conv + balpha[0])));

    ushortT* fb = F + (size_t)idx * KP;
    fb[256] = bfr(dwin[2][2]);
    fb[257] = bfr(gxc);
    fb[258] = bfr(gyc);
    float xc = -1.f + 2.f * (float)ww / 63.f;
    float yc = -1.f + 2.f * (float)hh / 63.f;
    const float l2w = 13.287712379549449f;  // log2(10000)
    #pragma unroll
    for (int i = 0; i < 16; i++) {
        float omega = exp2f(-(float)i * (l2w / 16.f));
        float px = xc * omega, py = yc * omega;
        fb[259 + i]      = bfr(__sinf(px));
        fb[259 + 16 + i] = bfr(__cosf(px));
        fb[259 + 32 + i] = bfr(__sinf(py));
        fb[259 + 48 + i] = bfr(__cosf(py));
    }
    #pragma unroll
    for (int z = 323; z < KP; z++) fb[z] = 0;
}

// ---------------- cast x -> F cols 0..255 (bf16, LDS transpose) ----------------
__global__ void k_cast(const float* __restrict__ x, ushortT* __restrict__ F) {
    __shared__ __align__(16) ushortT Tl[64][72];
    int nt = blockIdx.x * 64;
    int b = blockIdx.y >> 2, ct = (blockIdx.y & 3) * 64;
    int t = threadIdx.x;
    #pragma unroll
    for (int rep = 0; rep < 4; rep++) {
        int row = rep * 16 + (t >> 4), c4 = (t & 15) * 4;
        float4 f4 = *(const float4*)&x[((size_t)(b * 256 + ct + row)) * NPOS + nt + c4];
        Tl[c4 + 0][row] = bfr(f4.x);
        Tl[c4 + 1][row] = bfr(f4.y);
        Tl[c4 + 2][row] = bfr(f4.z);
        Tl[c4 + 3][row] = bfr(f4.w);
    }
    __syncthreads();
    #pragma unroll
    for (int rep = 0; rep < 2; rep++) {
        int slot = rep * 256 + t, row = slot >> 3, c8 = slot & 7;
        *(uint4*)&F[((size_t)(b * 4096 + nt + row)) * KP + ct + c8 * 8] = *(uint4*)&Tl[row][c8 * 8];
    }
}

// ---------------- combined weight Wc[1536][352] bf16 + bias fp32 ----------------
__global__ void k_wcprep(const float* __restrict__ wq, const float* __restrict__ wkv,
                         const float* __restrict__ whape, const float* __restrict__ bhape,
                         ushortT* __restrict__ Wc, float* __restrict__ biasc) {
    int idx = blockIdx.x * 256 + threadIdx.x;   // o*KP + k
    int o = idx / KP, k = idx % KP;
    float v = 0.f;
    if (o < 512) {
        if (k < 256) v = wq[o * 256 + k] * 0.18033688011112042f;  // 0.125 * log2(e)
        if (k == 0) biasc[o] = 0.f;
    } else if (o < 1024) {
        int r = o - 512;
        if (k < 257) v = wkv[r * 257 + k];
        if (k == 256)      v += whape[r * 67 + 64];
        else if (k == 257) v = whape[r * 67 + 65];
        else if (k == 258) v = whape[r * 67 + 66];
        else if (k >= 259 && k < 323) v = whape[r * 67 + (k - 259)];
        if (k == 0) biasc[o] = bhape[r];
    } else {
        int r = o - 512;
        if (k < 257) v = wkv[r * 257 + k];
        if (k == 0) biasc[o] = 0.f;
    }
    Wc[idx] = bfr(v);
}

// ---------------- wout -> bf16 ----------------
__global__ void k_wout(const float* __restrict__ wout, ushortT* __restrict__ woutb) {
    int idx = blockIdx.x * 256 + threadIdx.x;   // 131072
    woutb[idx] = bfr(wout[idx]);
}

// ---------------- GEMM1 (bf16 MFMA): [1536]x[352]x[8192] -> qT/kT/vv ----------------
__global__ __launch_bounds__(256) void k_gemm1(const ushortT* __restrict__ Wc, const ushortT* __restrict__ F,
                                               const float* __restrict__ biasc,
                                               ushortT* __restrict__ qT, ushortT* __restrict__ kT,
                                               ushortT* __restrict__ vv) {
    __shared__ __align__(16) ushortT Al[64][40];
    __shared__ __align__(16) ushortT Bl[64][40];
    __shared__ __align__(16) ushortT Vt[64][72];
    int mt = blockIdx.x * 64;
    int ot = blockIdx.y * 64;
    int t = threadIdx.x, w = t >> 6, lane = t & 63, u = lane & 15, quad = lane >> 4;
    int arow = t >> 2, ac8 = t & 3;
    v4f acc[4] = {};
    for (int k0 = 0; k0 < KP; k0 += 32) {
        __syncthreads();
        *(uint4*)&Al[arow][ac8 * 8] = *(const uint4*)&Wc[(size_t)(ot + arow) * KP + k0 + ac8 * 8];
        *(uint4*)&Bl[arow][ac8 * 8] = *(const uint4*)&F[(size_t)(mt + arow) * KP + k0 + ac8 * 8];
        __syncthreads();
        v8s a = *(v8s*)&Al[w * 16 + u][quad * 8];
        #pragma unroll
        for (int n4 = 0; n4 < 4; n4++) {
            v8s bb = *(v8s*)&Bl[n4 * 16 + u][quad * 8];
            acc[n4] = __builtin_amdgcn_mfma_f32_16x16x32_bf16(a, bb, acc[n4], 0, 0, 0);
        }
    }
    int obase = ot + w * 16 + quad * 4;
    float bo[4];
    #pragma unroll
    for (int r = 0; r < 4; r++) bo[r] = biasc[obase + r];
    if (ot < 1024) {
        int h = (ot >> 6) & 7;
        ushortT* dst = (ot < 512) ? qT : kT;
        #pragma unroll
        for (int n4 = 0; n4 < 4; n4++) {
            int m = mt + n4 * 16 + u;
            uint2 val;
            val.x = pack2bf(acc[n4][0] + bo[0], acc[n4][1] + bo[1]);
            val.y = pack2bf(acc[n4][2] + bo[2], acc[n4][3] + bo[3]);
            *(uint2*)&dst[((size_t)h * MTOT + m) * 64 + w * 16 + quad * 4] = val;
        }
    } else {
        __syncthreads();
        #pragma unroll
        for (int n4 = 0; n4 < 4; n4++) {
            int ml = n4 * 16 + u;
            #pragma unroll
            for (int r = 0; r < 4; r++) Vt[w * 16 + quad * 4 + r][ml] = bfr(acc[n4][r] + bo[r]);
        }
        __syncthreads();
        #pragma unroll
        for (int rep = 0; rep < 2; rep++) {
            int slot = rep * 256 + t, row = slot >> 3, c8 = slot & 7;
            *(uint4*)&vv[(size_t)(ot - 1024 + row) * MTOT + mt + c8 * 8] = *(uint4*)&Vt[row][c8 * 8];
        }
    }
}

// ---------------- flash attention: 64q/wave, LDS-staged K/V (double-buffered, 1 barrier/chunk),
// key-split-2 across blocks (partial unnormalized O + li; combined by k_comb) ----------------
#define LIDX(row, cb) (((row) << 6) + ((((cb) ^ ((row) & 7))) << 3))
__global__ __launch_bounds__(256, 2) void k_flash(const ushortT* __restrict__ qT,
                                                  const ushortT* __restrict__ kT,
                                                  const ushortT* __restrict__ vv,
                                                  float* __restrict__ Opart,
                                                  float* __restrict__ liPart) {
    __shared__ __align__(16) ushortT Kbuf[2][64 * 64];   // 8 KB each
    __shared__ __align__(16) ushortT Vbuf[2][64 * 64];
    __shared__ __align__(16) ushortT Pw[4][64 * 64];     // per-wave P strip

    int it = blockIdx.x;            // 0..15 (256-query tiles)
    int bh = blockIdx.y;
    int half = blockIdx.z;          // key half: 0 or 1
    int b = bh >> 3, h = bh & 7;
    int colbase = b * NPOS;
    int t = threadIdx.x, w = t >> 6, lane = t & 63, u = lane & 15, quad = lane >> 4;
    int qb = it * 256 + w * 64;     // wave's query base within batch

    const ushortT* Qg = qT + ((size_t)h * MTOT + colbase + qb) * 64;
    const ushortT* Kg = kT + ((size_t)h * MTOT + colbase + half * 2048) * 64;
    const ushortT* Vg = vv + ((size_t)(h * 64)) * MTOT + colbase + half * 2048;
    ushortT* P = &Pw[w][0];

    // staging slots (2 per thread for K, 2 for V)
    int row0 = t >> 3,        c80 = t & 7;        // slot t
    int row1 = (256 + t) >> 3, c81 = t & 7;       // slot 256+t (c8 same)

    // Q fragments resident in registers
    v8s bq[4][2];
    #pragma unroll
    for (int g = 0; g < 4; g++)
        #pragma unroll
        for (int hf = 0; hf < 2; hf++)
            bq[g][hf] = *(const v8s*)&Qg[(size_t)(g * 16 + u) * 64 + hf * 32 + quad * 8];

    float li[4] = {0.f, 0.f, 0.f, 0.f};
    v4f O[4][4] = {};   // [d4][g]

    // prologue: prefetch chunk 0
    uint4 kr0 = *(const uint4*)&Kg[(size_t)row0 * 64 + c80 * 8];
    uint4 kr1 = *(const uint4*)&Kg[(size_t)row1 * 64 + c81 * 8];
    uint4 vr0 = *(const uint4*)&Vg[(size_t)row0 * MTOT + c80 * 8];
    uint4 vr1 = *(const uint4*)&Vg[(size_t)row1 * MTOT + c81 * 8];

    for (int jc = 0; jc < 32; jc++) {
        int cur = jc & 1;
        // write staged regs to LDS buffer `cur`
        *(uint4*)&Kbuf[cur][LIDX(row0, c80)] = kr0;
        *(uint4*)&Kbuf[cur][LIDX(row1, c81)] = kr1;
        *(uint4*)&Vbuf[cur][LIDX(row0, c80)] = vr0;
        *(uint4*)&Vbuf[cur][LIDX(row1, c81)] = vr1;
        // prefetch next chunk (no wait — lands during compute)
        if (jc + 1 < 32) {
            int jb = (jc + 1) * 64;
            kr0 = *(const uint4*)&Kg[(size_t)(jb + row0) * 64 + c80 * 8];
            kr1 = *(const uint4*)&Kg[(size_t)(jb + row1) * 64 + c81 * 8];
            vr0 = *(const uint4*)&Vg[(size_t)row0 * MTOT + jb + c80 * 8];
            vr1 = *(const uint4*)&Vg[(size_t)row1 * MTOT + jb + c81 * 8];
        }
        __syncthreads();   // buffer `cur` complete for all waves

        const ushortT* Kb = &Kbuf[cur][0];
        const ushortT* Vb = &Vbuf[cur][0];

        // S^T strips + softmax
        #pragma unroll
        for (int k4 = 0; k4 < 4; k4++) {
            v8s ak0 = *(const v8s*)&Kb[LIDX(k4 * 16 + u, quad)];
            v8s ak1 = *(const v8s*)&Kb[LIDX(k4 * 16 + u, 4 + quad)];
            v4f st[4];
            #pragma unroll
            for (int g = 0; g < 4; g++) {
                st[g] = (v4f){0.f, 0.f, 0.f, 0.f};
                st[g] = __builtin_amdgcn_mfma_f32_16x16x32_bf16(ak0, bq[g][0], st[g], 0, 0, 0);
                st[g] = __builtin_amdgcn_mfma_f32_16x16x32_bf16(ak1, bq[g][1], st[g], 0, 0, 0);
            }
            #pragma unroll
            for (int g = 0; g < 4; g++) {
                float p0 = fexp2(st[g][0]);
                float p1 = fexp2(st[g][1]);
                float p2 = fexp2(st[g][2]);
                float p3 = fexp2(st[g][3]);
                li[g] += (p0 + p1) + (p2 + p3);
                uint2 pv; pv.x = pack2bf_t(p0, p1); pv.y = pack2bf_t(p2, p3);
                *(uint2*)&P[LIDX(g * 16 + u, k4 * 2 + (quad >> 1)) + (quad & 1) * 4] = pv;
            }
        }

        // O^T += V^T * P (per-wave P, lgkmcnt only)
        v8s bp[4][2];
        #pragma unroll
        for (int g = 0; g < 4; g++)
            #pragma unroll
            for (int ks = 0; ks < 2; ks++)
                bp[g][ks] = *(v8s*)&P[LIDX(g * 16 + u, ks * 4 + quad)];
        #pragma unroll
        for (int d4 = 0; d4 < 4; d4++) {
            v8s av0 = *(const v8s*)&Vb[LIDX(d4 * 16 + u, quad)];
            v8s av1 = *(const v8s*)&Vb[LIDX(d4 * 16 + u, 4 + quad)];
            #pragma unroll
            for (int g = 0; g < 4; g++) {
                O[d4][g] = __builtin_amdgcn_mfma_f32_16x16x32_bf16(av0, bp[g][0], O[d4][g], 0, 0, 0);
                O[d4][g] = __builtin_amdgcn_mfma_f32_16x16x32_bf16(av1, bp[g][1], O[d4][g], 0, 0, 0);
            }
        }
    }

    // epilogue: store UNNORMALIZED O (fp32) + li partials
    #pragma unroll
    for (int g = 0; g < 4; g++) {
        li[g] += __shfl_xor(li[g], 16, 64);
        li[g] += __shfl_xor(li[g], 32, 64);
        int q = qb + g * 16 + u;
        size_t m2 = (size_t)(half * 2 + b) * 4096 + q;   // = half*8192 + m
        size_t base = m2 * 512 + h * 64;
        #pragma unroll
        for (int d4 = 0; d4 < 4; d4++) {
            float4 o4;
            o4.x = O[d4][g][0]; o4.y = O[d4][g][1]; o4.z = O[d4][g][2]; o4.w = O[d4][g][3];
            *(float4*)&Opart[base + d4 * 16 + quad * 4] = o4;
        }
        if (quad == 0) liPart[m2 * 8 + h] = li[g];
    }
}

// ---------------- combine the two key-halves -> aoB bf16 [m][512] ----------------
__global__ __launch_bounds__(256) void k_comb(const float* __restrict__ Opart,
                                              const float* __restrict__ liPart,
                                              ushortT* __restrict__ aoB) {
    int tid = blockIdx.x * 256 + threadIdx.x;   // 8192*128
    int m = tid >> 7, c4 = (tid & 127) * 4, h = c4 >> 6;
    float l = liPart[(size_t)m * 8 + h] + liPart[(size_t)(8192 + m) * 8 + h];
    float inv = 1.f / l;
    float4 o0 = *(const float4*)&Opart[(size_t)m * 512 + c4];
    float4 o1 = *(const float4*)&Opart[(size_t)(8192 + m) * 512 + c4];
    uint2 val;
    val.x = pack2bf((o0.x + o1.x) * inv, (o0.y + o1.y) * inv);
    val.y = pack2bf((o0.z + o1.z) * inv, (o0.w + o1.w) * inv);
    *(uint2*)&aoB[(size_t)m * 512 + c4] = val;
}

// ---------------- GEMM2 (bf16 MFMA): out = x + (wout*AO + bout)*alpha ----------------
__global__ __launch_bounds__(256) void k_gemm2(const ushortT* __restrict__ woutb, const ushortT* __restrict__ aoB,
                                               const float* __restrict__ bout, const float* __restrict__ x,
                                               const float* __restrict__ alpha, float* __restrict__ out) {
    __shared__ __align__(16) ushortT Al[64][40];
    __shared__ __align__(16) ushortT Bl[64][40];
    int mt = blockIdx.x * 64;
    int ot = blockIdx.y * 64;
    int t = threadIdx.x, w = t >> 6, lane = t & 63, u = lane & 15, quad = lane >> 4;
    int arow = t >> 2, ac8 = t & 3;
    v4f acc[4] = {};
    for (int k0 = 0; k0 < 512; k0 += 32) {
        __syncthreads();
        *(uint4*)&Al[arow][ac8 * 8] = *(const uint4*)&woutb[(size_t)(ot + arow) * 512 + k0 + ac8 * 8];
        *(uint4*)&Bl[arow][ac8 * 8] = *(const uint4*)&aoB[(size_t)(mt + arow) * 512 + k0 + ac8 * 8];
        __syncthreads();
        v8s a = *(v8s*)&Al[w * 16 + u][quad * 8];
        #pragma unroll
        for (int n4 = 0; n4 < 4; n4++) {
            v8s bb = *(v8s*)&Bl[n4 * 16 + u][quad * 8];
            acc[n4] = __builtin_amdgcn_mfma_f32_16x16x32_bf16(a, bb, acc[n4], 0, 0, 0);
        }
    }
    int b = mt >> 12, n0 = mt & 4095;
    int obase = ot + w * 16 + quad * 4;
    float bo[4];
    #pragma unroll
    for (int r = 0; r < 4; r++) bo[r] = bout[obase + r];
    #pragma unroll
    for (int n4 = 0; n4 < 4; n4++) {
        int n = n0 + n4 * 16 + u;
        float al = alpha[(size_t)b * NPOS + n];
        #pragma unroll
        for (int r = 0; r < 4; r++) {
            size_t xi = ((size_t)(b * 256 + obase + r)) * NPOS + n;
            out[xi] = x[xi] + (acc[n4][r] + bo[r]) * al;
        }
    }
}

extern "C" void kernel_launch(void* const* d_in, const int* in_sizes, int n_in,
                              void* d_out, int out_size, void* d_ws, size_t ws_size,
                              hipStream_t stream) {
    const float* x      = (const float*)d_in[0];
    const float* dsm    = (const float*)d_in[1];
    const float* wq     = (const float*)d_in[2];
    const float* wkv    = (const float*)d_in[3];
    const float* wout   = (const float*)d_in[4];
    const float* bout   = (const float*)d_in[5];
    const float* whape  = (const float*)d_in[6];
    const float* bhape  = (const float*)d_in[7];
    const float* walpha = (const float*)d_in[8];
    const float* balpha = (const float*)d_in[9];
    float* out = (float*)d_out;
    float* ws  = (float*)d_ws;

    size_t off = 0;
    float* mm    = ws + off; off += 256;
    float* alpha = ws + off; off += (size_t)2 * NPOS;
    float* biasc = ws + off; off += 2048;
    float* Opart  = ws + off; off += (size_t)2 * MTOT * 512;     // fp32 partial O (33.5 MB)
    float* liPart = ws + off; off += (size_t)2 * MTOT * 8;       // fp32 partial li
    ushortT* F     = (ushortT*)(ws + off); off += (size_t)MTOT * KP / 2;
    ushortT* Wc    = (ushortT*)(ws + off); off += (size_t)1536 * KP / 2;
    ushortT* woutb = (ushortT*)(ws + off); off += (size_t)256 * 512 / 2;
    ushortT* qT    = (ushortT*)(ws + off); off += (size_t)8 * MTOT * 64 / 2;
    ushortT* kT    = (ushortT*)(ws + off); off += (size_t)8 * MTOT * 64 / 2;
    ushortT* vv    = (ushortT*)(ws + off); off += (size_t)512 * MTOT / 2;
    ushortT* aoB   = (ushortT*)(ws + off); off += (size_t)MTOT * 512 / 2;
    (void)in_sizes; (void)n_in; (void)out_size; (void)ws_size;

    k_minmax<<<2, 256, 0, stream>>>(dsm, mm);
    k_prep<<<32, 256, 0, stream>>>(dsm, mm, walpha, balpha, F, alpha);
    k_cast<<<dim3(64, 8), 256, 0, stream>>>(x, F);
    k_wcprep<<<(1536 * KP) / 256, 256, 0, stream>>>(wq, wkv, whape, bhape, Wc, biasc);
    k_wout<<<512, 256, 0, stream>>>(wout, woutb);
    k_gemm1<<<dim3(128, 24), 256, 0, stream>>>(Wc, F, biasc, qT, kT, vv);
    k_flash<<<dim3(16, 16, 2), 256, 0, stream>>>(qT, kT, vv, Opart, liPart);
    k_comb<<<4096, 256, 0, stream>>>(Opart, liPart, aoB);
    k_gemm2<<<dim3(128, 4), 256, 0, stream>>>(woutb, aoB, bout, x, alpha, out);
}